// Round 15
// baseline (141.403 us; speedup 1.0000x reference)
//
#include <hip/hip_runtime.h>
#include <hip/hip_bf16.h>

typedef __bf16 bf16;
typedef __bf16 bf16x4 __attribute__((ext_vector_type(4)));
typedef __bf16 bf16x8 __attribute__((ext_vector_type(8)));
typedef float  floatx4 __attribute__((ext_vector_type(4)));

#define D_MODEL   1024
#define NUM_HEADS 16
#define NUM_GROUPS 4
#define DK        64
#define SEQ_T     2048
#define BATCH     2
#define M_ROWS    (BATCH*SEQ_T)   // 4096
#define WINDOW    512
#define KV_DIM    (NUM_GROUPS*DK) // 256
#define N_QKV     (D_MODEL + 2*KV_DIM)  // 1536
// Q pre-scale: 1/sqrt(64) * log2(e)  (exp -> exp2 domain)
#define QSCALE    0.1803368801111204f
// log2(10000)/32
#define FREQ_C    0.4152410118609203f

#define GLDS16(g, l)                                                          \
    __builtin_amdgcn_global_load_lds(                                         \
        (const __attribute__((address_space(1))) void*)(g),                   \
        (__attribute__((address_space(3))) void*)(l), 16, 0, 0)

// ---------------------------------------------------------------------------
// Fused convert: 5 fp32 segments (x, WQ, WK, WV, WO) -> bf16 dsts.
// ---------------------------------------------------------------------------
__global__ __launch_bounds__(256)
void convert_all(const float* s0, bf16* d0, int c0,
                 const float* s1, bf16* d1, int c1,
                 const float* s2, bf16* d2, int c2,
                 const float* s3, bf16* d3, int c3,
                 const float* s4, bf16* d4, int c4)
{
    int id = blockIdx.x * 256 + threadIdx.x;
    const float* src; bf16* dst;
    if      (id < c0)         { src = s0; dst = d0; }
    else if ((id -= c0) < c1) { src = s1; dst = d1; }
    else if ((id -= c1) < c2) { src = s2; dst = d2; }
    else if ((id -= c2) < c3) { src = s3; dst = d3; }
    else if ((id -= c3) < c4) { src = s4; dst = d4; }
    else return;
    int i = id * 8;
    const float* s = src + i;
    float4 a = *(const float4*)s;
    float4 b = *(const float4*)(s + 4);
    bf16x8 v;
    v[0] = (bf16)a.x; v[1] = (bf16)a.y; v[2] = (bf16)a.z; v[3] = (bf16)a.w;
    v[4] = (bf16)b.x; v[5] = (bf16)b.y; v[6] = (bf16)b.z; v[7] = (bf16)b.w;
    *(bf16x8*)&dst[i] = v;
}

// ---------------------------------------------------------------------------
// bf16 GEMM, C = A @ W^T. 128x64 tile, 4 waves each 64x32 (4x2 acc), BK=64.
// glds staging + T2 XOR-swizzled LDS + XCD-panel-exclusive swizzle +
// counted vmcnt(6) double-buffer prefetch. [verbatim best config]
// mode 0: Q (rope+QSCALE) / K (rope) / V (transposed store into Vt) split.
// mode 1: single fp32 output Co.
// ---------------------------------------------------------------------------
__global__ __launch_bounds__(256, 3)
void gemm_t64(const bf16* __restrict__ A, const bf16* __restrict__ W, int K,
              bf16* __restrict__ Cq, bf16* __restrict__ Ck, bf16* __restrict__ Vt,
              float* __restrict__ Co, const int* __restrict__ pos, int mode)
{
    __shared__ bf16 As[2][128 * 64];   // 16 KB per buffer
    __shared__ bf16 Bs[2][64 * 64];    //  8 KB per buffer

    const int tid  = threadIdx.x;
    const int wave = tid >> 6;
    const int lane = tid & 63;
    const int lr   = lane & 15;
    const int quad = lane >> 4;

    // ---- XCD-panel-exclusive swizzle (bijective; gridDim.x % 8 == 0) ----
    const int nx    = (mode == 0) ? (N_QKV / 64) : (D_MODEL / 64);
    const int bid   = blockIdx.x;
    const int chunk = gridDim.x >> 3;
    const int v     = (bid & 7) * chunk + (bid >> 3);
    const int m0    = (v / nx) * 128;
    const int n0    = (v % nx) * 64;

    const int wm = (wave >> 1) * 64;
    const int wn = (wave & 1) * 32;

    // ---- staging geometry (pre-swizzled source, linear LDS dest) ----
    const int cr8 = lane >> 3;                       // row within 8-row chunk
    const int cc  = ((lane & 7) ^ cr8) * 8;          // swizzled global col (elems)
    const bf16* Ag = &A[(size_t)(m0 + cr8) * K + cc];
    const bf16* Wg = &W[(size_t)(n0 + cr8) * K + cc];

#define STAGE(buf, kk)                                                        \
    do {                                                                      \
        GLDS16(Ag + (size_t)((wave * 4 + 0) * 8) * K + (kk), &As[buf][(wave * 4 + 0) * 512]); \
        GLDS16(Ag + (size_t)((wave * 4 + 1) * 8) * K + (kk), &As[buf][(wave * 4 + 1) * 512]); \
        GLDS16(Ag + (size_t)((wave * 4 + 2) * 8) * K + (kk), &As[buf][(wave * 4 + 2) * 512]); \
        GLDS16(Ag + (size_t)((wave * 4 + 3) * 8) * K + (kk), &As[buf][(wave * 4 + 3) * 512]); \
        GLDS16(Wg + (size_t)((wave * 2 + 0) * 8) * K + (kk), &Bs[buf][(wave * 2 + 0) * 512]); \
        GLDS16(Wg + (size_t)((wave * 2 + 1) * 8) * K + (kk), &Bs[buf][(wave * 2 + 1) * 512]); \
    } while (0)

    // ---- fragment-read swizzled column offsets (lane-constant) ----
    const int ax0 = (quad ^ (lane & 7)) * 8;         // ks=0 col offset (elems)
    const int ax1 = ax0 ^ 32;                        // ks=1: col16 ^= 4

    floatx4 acc[4][2];
#pragma unroll
    for (int i = 0; i < 4; i++)
#pragma unroll
        for (int j = 0; j < 2; j++) acc[i][j] = (floatx4)(0.0f);

    // prologue: stage tile 0 (6 loads in flight; waited inside the loop)
    STAGE(0, 0);

    int cur = 0;
    for (int k0 = 0; k0 < K; k0 += 64) {
        if (k0 + 64 < K) {
            STAGE(cur ^ 1, k0 + 64);   // 6 new loads -> up to 12 outstanding
            __asm__ volatile("s_waitcnt vmcnt(6)" ::: "memory");
        } else {
            __asm__ volatile("s_waitcnt vmcnt(0)" ::: "memory");
        }
        __builtin_amdgcn_s_barrier();  // all waves' tile-cur data visible

        bf16x8 a0[4], a1[4], b0[2], b1[2];
#pragma unroll
        for (int mi = 0; mi < 4; mi++) {
            a0[mi] = *(const bf16x8*)&As[cur][(wm + mi * 16 + lr) * 64 + ax0];
            a1[mi] = *(const bf16x8*)&As[cur][(wm + mi * 16 + lr) * 64 + ax1];
        }
#pragma unroll
        for (int ni = 0; ni < 2; ni++) {
            b0[ni] = *(const bf16x8*)&Bs[cur][(wn + ni * 16 + lr) * 64 + ax0];
            b1[ni] = *(const bf16x8*)&Bs[cur][(wn + ni * 16 + lr) * 64 + ax1];
        }

#pragma unroll
        for (int mi = 0; mi < 4; mi++)
#pragma unroll
            for (int ni = 0; ni < 2; ni++) {
                acc[mi][ni] = __builtin_amdgcn_mfma_f32_16x16x32_bf16(
                    a0[mi], b0[ni], acc[mi][ni], 0, 0, 0);
                acc[mi][ni] = __builtin_amdgcn_mfma_f32_16x16x32_bf16(
                    a1[mi], b1[ni], acc[mi][ni], 0, 0, 0);
            }

        __builtin_amdgcn_s_barrier();
        cur ^= 1;
    }
#undef STAGE

    if (mode == 0) {
        if (n0 >= D_MODEL + KV_DIM) {
            // ---- V: store transposed into Vt[(bg*64+d)*SEQ_T + t] ----
            const int g  = (n0 - (D_MODEL + KV_DIM)) >> 6;   // 0..3
            const int b  = m0 >> 11;
            const int bg = b * 4 + g;
#pragma unroll
            for (int mi = 0; mi < 4; mi++) {
#pragma unroll
                for (int ni = 0; ni < 2; ni++) {
                    int d  = wn + ni * 16 + lr;
                    int t0 = (m0 & (SEQ_T - 1)) + wm + mi * 16 + quad * 4;
                    bf16x4 vv;
#pragma unroll
                    for (int r = 0; r < 4; r++) vv[r] = (bf16)acc[mi][ni][r];
                    *(bf16x4*)&Vt[((size_t)(bg * 64 + d)) * SEQ_T + t0] = vv;
                }
            }
        } else {
            // ---- Q / K: RoPE epilogue ----
            bf16* out; int ld, coff; float sc;
            if (n0 < D_MODEL) { out = Cq; ld = D_MODEL; coff = n0; sc = QSCALE; }
            else              { out = Ck; ld = KV_DIM;  coff = n0 - D_MODEL; sc = 1.0f; }
            float inv[2];
            float sgn = (lr & 1) ? 1.0f : -1.0f;
#pragma unroll
            for (int ni = 0; ni < 2; ni++) {
                int ip = (wn + ni * 16 + lr) >> 1;      // pair index 0..31 within head
                inv[ni] = exp2f(-(float)ip * FREQ_C);
            }
#pragma unroll
            for (int mi = 0; mi < 4; mi++) {
#pragma unroll
                for (int r = 0; r < 4; r++) {
                    int row = m0 + wm + mi * 16 + quad * 4 + r;
                    float p = (float)pos[row & (SEQ_T - 1)];
#pragma unroll
                    for (int ni = 0; ni < 2; ni++) {
                        float vv = acc[mi][ni][r];
                        float vp = __shfl_xor(vv, 1);
                        float ang = p * inv[ni];
                        float ss, cc2;
                        __sincosf(ang, &ss, &cc2);
                        vv = vv * cc2 + vp * ss * sgn;  // even: x1 c - x2 s ; odd: x1 s + x2 c
                        out[(size_t)row * ld + coff + wn + ni * 16 + lr] = (bf16)(vv * sc);
                    }
                }
            }
        }
    } else {
#pragma unroll
        for (int mi = 0; mi < 4; mi++)
#pragma unroll
            for (int ni = 0; ni < 2; ni++)
#pragma unroll
                for (int r = 0; r < 4; r++) {
                    int row = m0 + wm + mi * 16 + quad * 4 + r;
                    int col = n0 + wn + ni * 16 + lr;
                    Co[(size_t)row * D_MODEL + col] = acc[mi][ni][r];
                }
    }
}

// ---------------------------------------------------------------------------
// GQA-fused MFMA flash attention: P-in-register via swapped QK^T +
// PERMUTED-V LDS layout + setprio [= the 139.6 us best config].
// R14 delta: K/V LDS DOUBLE-BUFFER (T3 minimum 2-phase for attn). Per step:
// write NEXT tile into buf[cur^1] (regs prefetched last step) concurrently
// with computing from buf[cur]; ONE barrier per step (was two + exposed
// writes). Hazard-safe: buf[cur^1] was last read a full step ago (its
// readers passed the prior barrier); this step's writes are sealed by this
// step's barrier before next step reads them. LDS 41.5 KB.
// ---------------------------------------------------------------------------
__global__ __launch_bounds__(256)
void attn_mfma(const bf16* __restrict__ Q, const bf16* __restrict__ K,
               const bf16* __restrict__ Vt_g, bf16* __restrict__ AO)
{
    const int ST = 72;
    __shared__ bf16 Ks[2][64 * ST];
    __shared__ bf16 Vt[2][80 * ST];     // row 64 = ones, 65-79 zeros

    const int tid  = threadIdx.x;
    const int wave = tid >> 6;
    const int lane = tid & 63;
    const int lr   = lane & 15;
    const int quad = lane >> 4;
    const int bg = blockIdx.y;
    const int b = bg >> 2, g = bg & 3;
    const int h = g * 4 + wave;
    const int q0 = blockIdx.x * 32;

    bf16x8 qf[2][2];
#pragma unroll
    for (int mi = 0; mi < 2; mi++)
#pragma unroll
        for (int ks = 0; ks < 2; ks++)
            qf[mi][ks] = *(const bf16x8*)
                &Q[((size_t)(b * SEQ_T + q0 + mi * 16 + lr)) * D_MODEL
                   + h * 64 + ks * 32 + quad * 8];

#pragma unroll
    for (int bb = 0; bb < 2; bb++) {
        for (int i = tid; i < 15 * ST; i += 256) Vt[bb][65 * ST + i] = (bf16)0.0f;
        if (tid < ST) Vt[bb][64 * ST + tid] = (bf16)(tid < 64 ? 1.0f : 0.0f);
    }

    floatx4 o[2][5];
#pragma unroll
    for (int mi = 0; mi < 2; mi++)
#pragma unroll
        for (int nt = 0; nt < 5; nt++) o[mi][nt] = (floatx4)(0.0f);

    const int t0   = (q0 >= WINDOW) ? ((q0 - WINDOW) & ~63) : 0;
    const int last = q0 & ~63;

    // per-thread staging slots: i=0,1 -> c = tid + i*256, row c>>3, col (c&7)*8
    const int srow0 = tid >> 3,         scol0 = (tid & 7) * 8;
    const int srow1 = (tid + 256) >> 3, scol1 = ((tid + 256) & 7) * 8;

    // permuted-V write offsets: slice base + ((wc&15)>>2)*8 + (wc>>4)*4
    const int wc0 = scol0 & 31;
    const int w00 = (scol0 & ~31) + ((wc0 & 15) >> 2) * 8 + (wc0 >> 4) * 4;
    const int wc1 = scol1 & 31;
    const int w10 = (scol1 & ~31) + ((wc1 & 15) >> 2) * 8 + (wc1 >> 4) * 4;

    bf16x8 kreg[2], vreg[2];
#define LOADKV(jn)                                                            \
    do {                                                                      \
        kreg[0] = *(const bf16x8*)&K[((size_t)(b * SEQ_T + (jn) + srow0)) * KV_DIM + g * 64 + scol0]; \
        vreg[0] = *(const bf16x8*)&Vt_g[((size_t)(bg * 64 + srow0)) * SEQ_T + (jn) + scol0];          \
        kreg[1] = *(const bf16x8*)&K[((size_t)(b * SEQ_T + (jn) + srow1)) * KV_DIM + g * 64 + scol1]; \
        vreg[1] = *(const bf16x8*)&Vt_g[((size_t)(bg * 64 + srow1)) * SEQ_T + (jn) + scol1];          \
    } while (0)

#define WRITEBUF(bb)                                                          \
    do {                                                                      \
        *(bf16x8*)&Ks[bb][srow0 * ST + scol0] = kreg[0];                      \
        *(bf16x8*)&Ks[bb][srow1 * ST + scol1] = kreg[1];                      \
        *(bf16x4*)&Vt[bb][srow0 * ST + w00] =                                 \
            __builtin_shufflevector(vreg[0], vreg[0], 0, 1, 2, 3);            \
        *(bf16x4*)&Vt[bb][srow0 * ST + w00 + 8] =                             \
            __builtin_shufflevector(vreg[0], vreg[0], 4, 5, 6, 7);            \
        *(bf16x4*)&Vt[bb][srow1 * ST + w10] =                                 \
            __builtin_shufflevector(vreg[1], vreg[1], 0, 1, 2, 3);            \
        *(bf16x4*)&Vt[bb][srow1 * ST + w10 + 8] =                             \
            __builtin_shufflevector(vreg[1], vreg[1], 4, 5, 6, 7);            \
    } while (0)

    // prologue: tile t0 into buf0; prefetch tile t0+64 into regs
    LOADKV(t0);
    WRITEBUF(0);
    if (t0 + 64 <= last) LOADKV(t0 + 64);
    __syncthreads();

    int cur = 0;
    for (int j0 = t0; j0 <= last; j0 += 64) {
        const bool mC = (j0 == last);
        const bool mW = (q0 >= WINDOW) && (j0 == t0);

        // write next tile (regs) into the other buffer; prefetch tile+2
        if (j0 + 64 <= last) {
            WRITEBUF(cur ^ 1);
            if (j0 + 128 <= last) LOADKV(j0 + 128);
        }

        // ---- QK^T swapped: lane holds S[key=nt*16+quad*4+r][q=mi*16+lr] ----
        floatx4 s2[4][2];
#pragma unroll
        for (int nt = 0; nt < 4; nt++)
#pragma unroll
            for (int mi = 0; mi < 2; mi++) s2[nt][mi] = (floatx4)(0.0f);
        __builtin_amdgcn_s_setprio(1);
#pragma unroll
        for (int ks = 0; ks < 2; ks++) {
#pragma unroll
            for (int nt = 0; nt < 4; nt++) {
                bf16x8 kf = *(const bf16x8*)&Ks[cur][(nt * 16 + lr) * ST + ks * 32 + quad * 8];
                s2[nt][0] = __builtin_amdgcn_mfma_f32_16x16x32_bf16(kf, qf[0][ks], s2[nt][0], 0, 0, 0);
                s2[nt][1] = __builtin_amdgcn_mfma_f32_16x16x32_bf16(kf, qf[1][ks], s2[nt][1], 0, 0, 0);
            }
        }
        __builtin_amdgcn_s_setprio(0);

        if (mC) {
#pragma unroll
            for (int nt = 0; nt < 4; nt++)
#pragma unroll
                for (int mi = 0; mi < 2; mi++) {
                    int qi_ = q0 + mi * 16 + lr;
#pragma unroll
                    for (int r = 0; r < 4; r++) {
                        int key = j0 + nt * 16 + quad * 4 + r;
                        s2[nt][mi][r] = (key <= qi_) ? s2[nt][mi][r] : -1e30f;
                    }
                }
        } else if (mW) {
#pragma unroll
            for (int nt = 0; nt < 4; nt++)
#pragma unroll
                for (int mi = 0; mi < 2; mi++) {
                    int qi_ = q0 + mi * 16 + lr;
#pragma unroll
                    for (int r = 0; r < 4; r++) {
                        int key = j0 + nt * 16 + quad * 4 + r;
                        s2[nt][mi][r] = (qi_ - key <= WINDOW) ? s2[nt][mi][r] : -1e30f;
                    }
                }
        }

        // ---- exp2 + lane-local pack into key-permuted A-frags ----
        bf16x8 pa[2][2];
#pragma unroll
        for (int mi = 0; mi < 2; mi++)
#pragma unroll
            for (int ks = 0; ks < 2; ks++)
#pragma unroll
                for (int r = 0; r < 4; r++) {
                    pa[mi][ks][r]     = (bf16)exp2f(s2[2 * ks][mi][r]);
                    pa[mi][ks][r + 4] = (bf16)exp2f(s2[2 * ks + 1][mi][r]);
                }

        // ---- PV: single b128 V-read (permuted layout matches kappa) ----
        __builtin_amdgcn_s_setprio(1);
#pragma unroll
        for (int ks = 0; ks < 2; ks++) {
#pragma unroll
            for (int nt = 0; nt < 5; nt++) {
                bf16x8 vf = *(const bf16x8*)&Vt[cur][(nt * 16 + lr) * ST + ks * 32 + quad * 8];
                o[0][nt] = __builtin_amdgcn_mfma_f32_16x16x32_bf16(pa[0][ks], vf, o[0][nt], 0, 0, 0);
                o[1][nt] = __builtin_amdgcn_mfma_f32_16x16x32_bf16(pa[1][ks], vf, o[1][nt], 0, 0, 0);
            }
        }
        __builtin_amdgcn_s_setprio(0);

        __syncthreads();               // seal this step's writes + reads
        cur ^= 1;
    }
#undef LOADKV
#undef WRITEBUF

#pragma unroll
    for (int mi = 0; mi < 2; mi++)
#pragma unroll
        for (int r = 0; r < 4; r++) {
            float l = __shfl(o[mi][4][r], lane & 48);
            float invl = 1.0f / l;
            int row = q0 + mi * 16 + quad * 4 + r;
#pragma unroll
            for (int nt = 0; nt < 4; nt++)
                AO[((size_t)(b * SEQ_T + row)) * D_MODEL + h * 64 + nt * 16 + lr] =
                    (bf16)(o[mi][nt][r] * invl);
        }
}

// ---------------------------------------------------------------------------
extern "C" void kernel_launch(void* const* d_in, const int* in_sizes, int n_in,
                              void* d_out, int out_size, void* d_ws, size_t ws_size,
                              hipStream_t stream)
{
    const float* x  = (const float*)d_in[0];
    const float* WQ = (const float*)d_in[1];
    const float* WK = (const float*)d_in[2];
    const float* WV = (const float*)d_in[3];
    const float* WO = (const float*)d_in[4];
    const int*  pos = (const int*)d_in[5];

    // ws: Qw 8MB | Kw 2MB | Vt_g 2MB | xb/AO 8MB | Wqkv 3MB | WOb 2MB
    char* ws   = (char*)d_ws;
    bf16* Qw   = (bf16*)ws;
    bf16* Kw   = (bf16*)(ws + (size_t) 8 * 1024 * 1024);
    bf16* Vt_g = (bf16*)(ws + (size_t)10 * 1024 * 1024);
    bf16* xb   = (bf16*)(ws + (size_t)12 * 1024 * 1024);
    bf16* AO   = xb;                                        // overlay (xb dead)
    bf16* Wqkv = (bf16*)(ws + (size_t)20 * 1024 * 1024);
    bf16* WOb  = (bf16*)(ws + (size_t)23 * 1024 * 1024);

    const int cx = (M_ROWS * D_MODEL) / 8;
    const int cq = (D_MODEL * D_MODEL) / 8;
    const int ck = (KV_DIM * D_MODEL) / 8;
    const int ctot = cx + cq + 2 * ck + cq;
    convert_all<<<ctot / 256, 256, 0, stream>>>(
        x, xb, cx,
        WQ, Wqkv, cq,
        WK, Wqkv + (size_t)D_MODEL * D_MODEL, ck,
        WV, Wqkv + (size_t)(D_MODEL + KV_DIM) * D_MODEL, ck,
        WO, WOb, cq);

    // fused QKV projection + RoPE epilogue + V-transpose (1-D grid, XCD swz)
    gemm_t64<<<(N_QKV / 64) * (M_ROWS / 128), 256, 0, stream>>>(
        xb, Wqkv, D_MODEL, Qw, Kw, Vt_g, nullptr, pos, 0);

    // GQA-fused attention (P-in-register + permuted-V + dbuf + setprio)
    attn_mfma<<<dim3(SEQ_T / 32, BATCH * NUM_GROUPS), 256, 0, stream>>>(
        Qw, Kw, Vt_g, AO);

    // output projection -> fp32 d_out (1-D grid, XCD swz)
    gemm_t64<<<(D_MODEL / 64) * (M_ROWS / 128), 256, 0, stream>>>(
        AO, WOb, D_MODEL, nullptr, nullptr, nullptr, (float*)d_out, pos, 1);
}

// Round 16
// 137.577 us; speedup vs baseline: 1.0278x; 1.0278x over previous
//
#include <hip/hip_runtime.h>
#include <hip/hip_bf16.h>

typedef __bf16 bf16;
typedef __bf16 bf16x4 __attribute__((ext_vector_type(4)));
typedef __bf16 bf16x8 __attribute__((ext_vector_type(8)));
typedef float  floatx4 __attribute__((ext_vector_type(4)));

#define D_MODEL   1024
#define NUM_HEADS 16
#define NUM_GROUPS 4
#define DK        64
#define SEQ_T     2048
#define BATCH     2
#define M_ROWS    (BATCH*SEQ_T)   // 4096
#define WINDOW    512
#define KV_DIM    (NUM_GROUPS*DK) // 256
#define N_QKV     (D_MODEL + 2*KV_DIM)  // 1536
// Q pre-scale: 1/sqrt(64) * log2(e)  (exp -> exp2 domain)
#define QSCALE    0.1803368801111204f
// log2(10000)/32
#define FREQ_C    0.4152410118609203f

#define GLDS16(g, l)                                                          \
    __builtin_amdgcn_global_load_lds(                                         \
        (const __attribute__((address_space(1))) void*)(g),                   \
        (__attribute__((address_space(3))) void*)(l), 16, 0, 0)

// ---------------------------------------------------------------------------
// Fused convert: 5 fp32 segments (x, WQ, WK, WV, WO) -> bf16 dsts.
// ---------------------------------------------------------------------------
__global__ __launch_bounds__(256)
void convert_all(const float* s0, bf16* d0, int c0,
                 const float* s1, bf16* d1, int c1,
                 const float* s2, bf16* d2, int c2,
                 const float* s3, bf16* d3, int c3,
                 const float* s4, bf16* d4, int c4)
{
    int id = blockIdx.x * 256 + threadIdx.x;
    const float* src; bf16* dst;
    if      (id < c0)         { src = s0; dst = d0; }
    else if ((id -= c0) < c1) { src = s1; dst = d1; }
    else if ((id -= c1) < c2) { src = s2; dst = d2; }
    else if ((id -= c2) < c3) { src = s3; dst = d3; }
    else if ((id -= c3) < c4) { src = s4; dst = d4; }
    else return;
    int i = id * 8;
    const float* s = src + i;
    float4 a = *(const float4*)s;
    float4 b = *(const float4*)(s + 4);
    bf16x8 v;
    v[0] = (bf16)a.x; v[1] = (bf16)a.y; v[2] = (bf16)a.z; v[3] = (bf16)a.w;
    v[4] = (bf16)b.x; v[5] = (bf16)b.y; v[6] = (bf16)b.z; v[7] = (bf16)b.w;
    *(bf16x8*)&dst[i] = v;
}

// ---------------------------------------------------------------------------
// bf16 GEMM, C = A @ W^T. 128x64 tile, 4 waves each 64x32 (4x2 acc), BK=64.
// glds staging + T2 XOR-swizzled LDS + XCD-panel-exclusive swizzle +
// counted vmcnt(6) double-buffer prefetch. [the verified best GEMM config]
// mode 0: Q (rope+QSCALE) / K (rope) / V (transposed store into Vt) split.
// mode 1: single fp32 output Co.
// ---------------------------------------------------------------------------
__global__ __launch_bounds__(256, 3)
void gemm_t64(const bf16* __restrict__ A, const bf16* __restrict__ W, int K,
              bf16* __restrict__ Cq, bf16* __restrict__ Ck, bf16* __restrict__ Vt,
              float* __restrict__ Co, const int* __restrict__ pos, int mode)
{
    __shared__ bf16 As[2][128 * 64];   // 16 KB per buffer
    __shared__ bf16 Bs[2][64 * 64];    //  8 KB per buffer

    const int tid  = threadIdx.x;
    const int wave = tid >> 6;
    const int lane = tid & 63;
    const int lr   = lane & 15;
    const int quad = lane >> 4;

    // ---- XCD-panel-exclusive swizzle (bijective; gridDim.x % 8 == 0) ----
    const int nx    = (mode == 0) ? (N_QKV / 64) : (D_MODEL / 64);
    const int bid   = blockIdx.x;
    const int chunk = gridDim.x >> 3;
    const int v     = (bid & 7) * chunk + (bid >> 3);
    const int m0    = (v / nx) * 128;
    const int n0    = (v % nx) * 64;

    const int wm = (wave >> 1) * 64;
    const int wn = (wave & 1) * 32;

    // ---- staging geometry (pre-swizzled source, linear LDS dest) ----
    const int cr8 = lane >> 3;                       // row within 8-row chunk
    const int cc  = ((lane & 7) ^ cr8) * 8;          // swizzled global col (elems)
    const bf16* Ag = &A[(size_t)(m0 + cr8) * K + cc];
    const bf16* Wg = &W[(size_t)(n0 + cr8) * K + cc];

#define STAGE(buf, kk)                                                        \
    do {                                                                      \
        GLDS16(Ag + (size_t)((wave * 4 + 0) * 8) * K + (kk), &As[buf][(wave * 4 + 0) * 512]); \
        GLDS16(Ag + (size_t)((wave * 4 + 1) * 8) * K + (kk), &As[buf][(wave * 4 + 1) * 512]); \
        GLDS16(Ag + (size_t)((wave * 4 + 2) * 8) * K + (kk), &As[buf][(wave * 4 + 2) * 512]); \
        GLDS16(Ag + (size_t)((wave * 4 + 3) * 8) * K + (kk), &As[buf][(wave * 4 + 3) * 512]); \
        GLDS16(Wg + (size_t)((wave * 2 + 0) * 8) * K + (kk), &Bs[buf][(wave * 2 + 0) * 512]); \
        GLDS16(Wg + (size_t)((wave * 2 + 1) * 8) * K + (kk), &Bs[buf][(wave * 2 + 1) * 512]); \
    } while (0)

    // ---- fragment-read swizzled column offsets (lane-constant) ----
    const int ax0 = (quad ^ (lane & 7)) * 8;         // ks=0 col offset (elems)
    const int ax1 = ax0 ^ 32;                        // ks=1: col16 ^= 4

    floatx4 acc[4][2];
#pragma unroll
    for (int i = 0; i < 4; i++)
#pragma unroll
        for (int j = 0; j < 2; j++) acc[i][j] = (floatx4)(0.0f);

    // prologue: stage tile 0 (6 loads in flight; waited inside the loop)
    STAGE(0, 0);

    int cur = 0;
    for (int k0 = 0; k0 < K; k0 += 64) {
        if (k0 + 64 < K) {
            STAGE(cur ^ 1, k0 + 64);   // 6 new loads -> up to 12 outstanding
            __asm__ volatile("s_waitcnt vmcnt(6)" ::: "memory");
        } else {
            __asm__ volatile("s_waitcnt vmcnt(0)" ::: "memory");
        }
        __builtin_amdgcn_s_barrier();  // all waves' tile-cur data visible

        bf16x8 a0[4], a1[4], b0[2], b1[2];
#pragma unroll
        for (int mi = 0; mi < 4; mi++) {
            a0[mi] = *(const bf16x8*)&As[cur][(wm + mi * 16 + lr) * 64 + ax0];
            a1[mi] = *(const bf16x8*)&As[cur][(wm + mi * 16 + lr) * 64 + ax1];
        }
#pragma unroll
        for (int ni = 0; ni < 2; ni++) {
            b0[ni] = *(const bf16x8*)&Bs[cur][(wn + ni * 16 + lr) * 64 + ax0];
            b1[ni] = *(const bf16x8*)&Bs[cur][(wn + ni * 16 + lr) * 64 + ax1];
        }

#pragma unroll
        for (int mi = 0; mi < 4; mi++)
#pragma unroll
            for (int ni = 0; ni < 2; ni++) {
                acc[mi][ni] = __builtin_amdgcn_mfma_f32_16x16x32_bf16(
                    a0[mi], b0[ni], acc[mi][ni], 0, 0, 0);
                acc[mi][ni] = __builtin_amdgcn_mfma_f32_16x16x32_bf16(
                    a1[mi], b1[ni], acc[mi][ni], 0, 0, 0);
            }

        __builtin_amdgcn_s_barrier();
        cur ^= 1;
    }
#undef STAGE

    if (mode == 0) {
        if (n0 >= D_MODEL + KV_DIM) {
            // ---- V: store transposed into Vt[(bg*64+d)*SEQ_T + t] ----
            const int g  = (n0 - (D_MODEL + KV_DIM)) >> 6;   // 0..3
            const int b  = m0 >> 11;
            const int bg = b * 4 + g;
#pragma unroll
            for (int mi = 0; mi < 4; mi++) {
#pragma unroll
                for (int ni = 0; ni < 2; ni++) {
                    int d  = wn + ni * 16 + lr;
                    int t0 = (m0 & (SEQ_T - 1)) + wm + mi * 16 + quad * 4;
                    bf16x4 vv;
#pragma unroll
                    for (int r = 0; r < 4; r++) vv[r] = (bf16)acc[mi][ni][r];
                    *(bf16x4*)&Vt[((size_t)(bg * 64 + d)) * SEQ_T + t0] = vv;
                }
            }
        } else {
            // ---- Q / K: RoPE epilogue ----
            bf16* out; int ld, coff; float sc;
            if (n0 < D_MODEL) { out = Cq; ld = D_MODEL; coff = n0; sc = QSCALE; }
            else              { out = Ck; ld = KV_DIM;  coff = n0 - D_MODEL; sc = 1.0f; }
            float inv[2];
            float sgn = (lr & 1) ? 1.0f : -1.0f;
#pragma unroll
            for (int ni = 0; ni < 2; ni++) {
                int ip = (wn + ni * 16 + lr) >> 1;      // pair index 0..31 within head
                inv[ni] = exp2f(-(float)ip * FREQ_C);
            }
#pragma unroll
            for (int mi = 0; mi < 4; mi++) {
#pragma unroll
                for (int r = 0; r < 4; r++) {
                    int row = m0 + wm + mi * 16 + quad * 4 + r;
                    float p = (float)pos[row & (SEQ_T - 1)];
#pragma unroll
                    for (int ni = 0; ni < 2; ni++) {
                        float vv = acc[mi][ni][r];
                        float vp = __shfl_xor(vv, 1);
                        float ang = p * inv[ni];
                        float ss, cc2;
                        __sincosf(ang, &ss, &cc2);
                        vv = vv * cc2 + vp * ss * sgn;  // even: x1 c - x2 s ; odd: x1 s + x2 c
                        out[(size_t)row * ld + coff + wn + ni * 16 + lr] = (bf16)(vv * sc);
                    }
                }
            }
        }
    } else {
#pragma unroll
        for (int mi = 0; mi < 4; mi++)
#pragma unroll
            for (int ni = 0; ni < 2; ni++)
#pragma unroll
                for (int r = 0; r < 4; r++) {
                    int row = m0 + wm + mi * 16 + quad * 4 + r;
                    int col = n0 + wn + ni * 16 + lr;
                    Co[(size_t)row * D_MODEL + col] = acc[mi][ni][r];
                }
    }
}

// ---------------------------------------------------------------------------
// GQA-fused MFMA flash attention: P-in-register via swapped QK^T +
// PERMUTED-V LDS layout + T14 reg-prefetch + setprio.
// [the verified best attention config: 2-barrier step structure; R14's
//  dbuf and R10's QBLK=16 both measured slower]
// ---------------------------------------------------------------------------
__global__ __launch_bounds__(256)
void attn_mfma(const bf16* __restrict__ Q, const bf16* __restrict__ K,
               const bf16* __restrict__ Vt_g, bf16* __restrict__ AO)
{
    const int ST = 72;
    __shared__ bf16 Ks[64 * ST];
    __shared__ bf16 Vt[80 * ST];        // row 64 = ones, 65-79 zeros

    const int tid  = threadIdx.x;
    const int wave = tid >> 6;
    const int lane = tid & 63;
    const int lr   = lane & 15;
    const int quad = lane >> 4;
    const int bg = blockIdx.y;
    const int b = bg >> 2, g = bg & 3;
    const int h = g * 4 + wave;
    const int q0 = blockIdx.x * 32;

    bf16x8 qf[2][2];
#pragma unroll
    for (int mi = 0; mi < 2; mi++)
#pragma unroll
        for (int ks = 0; ks < 2; ks++)
            qf[mi][ks] = *(const bf16x8*)
                &Q[((size_t)(b * SEQ_T + q0 + mi * 16 + lr)) * D_MODEL
                   + h * 64 + ks * 32 + quad * 8];

    for (int i = tid; i < 15 * ST; i += 256) Vt[65 * ST + i] = (bf16)0.0f;
    if (tid < ST) Vt[64 * ST + tid] = (bf16)(tid < 64 ? 1.0f : 0.0f);

    floatx4 o[2][5];
#pragma unroll
    for (int mi = 0; mi < 2; mi++)
#pragma unroll
        for (int nt = 0; nt < 5; nt++) o[mi][nt] = (floatx4)(0.0f);

    const int t0   = (q0 >= WINDOW) ? ((q0 - WINDOW) & ~63) : 0;
    const int last = q0 & ~63;

    // per-thread staging slots: i=0,1 -> c = tid + i*256, row c>>3, col (c&7)*8
    const int srow0 = tid >> 3,         scol0 = (tid & 7) * 8;
    const int srow1 = (tid + 256) >> 3, scol1 = ((tid + 256) & 7) * 8;

    // permuted-V write offsets: slice base + ((wc&15)>>2)*8 + (wc>>4)*4
    const int wc0 = scol0 & 31;
    const int w00 = (scol0 & ~31) + ((wc0 & 15) >> 2) * 8 + (wc0 >> 4) * 4;
    const int wc1 = scol1 & 31;
    const int w10 = (scol1 & ~31) + ((wc1 & 15) >> 2) * 8 + (wc1 >> 4) * 4;

    bf16x8 kreg[2], vreg[2];
#define LOADKV(jn)                                                            \
    do {                                                                      \
        kreg[0] = *(const bf16x8*)&K[((size_t)(b * SEQ_T + (jn) + srow0)) * KV_DIM + g * 64 + scol0]; \
        vreg[0] = *(const bf16x8*)&Vt_g[((size_t)(bg * 64 + srow0)) * SEQ_T + (jn) + scol0];          \
        kreg[1] = *(const bf16x8*)&K[((size_t)(b * SEQ_T + (jn) + srow1)) * KV_DIM + g * 64 + scol1]; \
        vreg[1] = *(const bf16x8*)&Vt_g[((size_t)(bg * 64 + srow1)) * SEQ_T + (jn) + scol1];          \
    } while (0)

    LOADKV(t0);

    for (int j0 = t0; j0 <= last; j0 += 64) {
        const bool mC = (j0 == last);
        const bool mW = (q0 >= WINDOW) && (j0 == t0);
        __syncthreads();                      // prev compute done with LDS
        *(bf16x8*)&Ks[srow0 * ST + scol0] = kreg[0];
        *(bf16x8*)&Ks[srow1 * ST + scol1] = kreg[1];
        // permuted V: keys c..c+3 -> slots w0..w0+3 ; keys c+4..c+7 -> w0+8..
        *(bf16x4*)&Vt[srow0 * ST + w00] =
            __builtin_shufflevector(vreg[0], vreg[0], 0, 1, 2, 3);
        *(bf16x4*)&Vt[srow0 * ST + w00 + 8] =
            __builtin_shufflevector(vreg[0], vreg[0], 4, 5, 6, 7);
        *(bf16x4*)&Vt[srow1 * ST + w10] =
            __builtin_shufflevector(vreg[1], vreg[1], 0, 1, 2, 3);
        *(bf16x4*)&Vt[srow1 * ST + w10 + 8] =
            __builtin_shufflevector(vreg[1], vreg[1], 4, 5, 6, 7);
        if (j0 + 64 <= last) LOADKV(j0 + 64); // prefetch next tile into regs
        __syncthreads();                      // LDS tile ready

        // ---- QK^T swapped: lane holds S[key=nt*16+quad*4+r][q=mi*16+lr] ----
        floatx4 s2[4][2];
#pragma unroll
        for (int nt = 0; nt < 4; nt++)
#pragma unroll
            for (int mi = 0; mi < 2; mi++) s2[nt][mi] = (floatx4)(0.0f);
        __builtin_amdgcn_s_setprio(1);
#pragma unroll
        for (int ks = 0; ks < 2; ks++) {
#pragma unroll
            for (int nt = 0; nt < 4; nt++) {
                bf16x8 kf = *(const bf16x8*)&Ks[(nt * 16 + lr) * ST + ks * 32 + quad * 8];
                s2[nt][0] = __builtin_amdgcn_mfma_f32_16x16x32_bf16(kf, qf[0][ks], s2[nt][0], 0, 0, 0);
                s2[nt][1] = __builtin_amdgcn_mfma_f32_16x16x32_bf16(kf, qf[1][ks], s2[nt][1], 0, 0, 0);
            }
        }
        __builtin_amdgcn_s_setprio(0);

        if (mC) {
#pragma unroll
            for (int nt = 0; nt < 4; nt++)
#pragma unroll
                for (int mi = 0; mi < 2; mi++) {
                    int qi_ = q0 + mi * 16 + lr;
#pragma unroll
                    for (int r = 0; r < 4; r++) {
                        int key = j0 + nt * 16 + quad * 4 + r;
                        s2[nt][mi][r] = (key <= qi_) ? s2[nt][mi][r] : -1e30f;
                    }
                }
        } else if (mW) {
#pragma unroll
            for (int nt = 0; nt < 4; nt++)
#pragma unroll
                for (int mi = 0; mi < 2; mi++) {
                    int qi_ = q0 + mi * 16 + lr;
#pragma unroll
                    for (int r = 0; r < 4; r++) {
                        int key = j0 + nt * 16 + quad * 4 + r;
                        s2[nt][mi][r] = (qi_ - key <= WINDOW) ? s2[nt][mi][r] : -1e30f;
                    }
                }
        }

        // ---- exp2 + lane-local pack into key-permuted A-frags ----
        bf16x8 pa[2][2];
#pragma unroll
        for (int mi = 0; mi < 2; mi++)
#pragma unroll
            for (int ks = 0; ks < 2; ks++)
#pragma unroll
                for (int r = 0; r < 4; r++) {
                    pa[mi][ks][r]     = (bf16)exp2f(s2[2 * ks][mi][r]);
                    pa[mi][ks][r + 4] = (bf16)exp2f(s2[2 * ks + 1][mi][r]);
                }

        // ---- PV: single b128 V-read (permuted layout matches kappa) ----
        __builtin_amdgcn_s_setprio(1);
#pragma unroll
        for (int ks = 0; ks < 2; ks++) {
#pragma unroll
            for (int nt = 0; nt < 5; nt++) {
                bf16x8 vf = *(const bf16x8*)&Vt[(nt * 16 + lr) * ST + ks * 32 + quad * 8];
                o[0][nt] = __builtin_amdgcn_mfma_f32_16x16x32_bf16(pa[0][ks], vf, o[0][nt], 0, 0, 0);
                o[1][nt] = __builtin_amdgcn_mfma_f32_16x16x32_bf16(pa[1][ks], vf, o[1][nt], 0, 0, 0);
            }
        }
        __builtin_amdgcn_s_setprio(0);
    }
#undef LOADKV

#pragma unroll
    for (int mi = 0; mi < 2; mi++)
#pragma unroll
        for (int r = 0; r < 4; r++) {
            float l = __shfl(o[mi][4][r], lane & 48);
            float invl = 1.0f / l;
            int row = q0 + mi * 16 + quad * 4 + r;
#pragma unroll
            for (int nt = 0; nt < 4; nt++)
                AO[((size_t)(b * SEQ_T + row)) * D_MODEL + h * 64 + nt * 16 + lr] =
                    (bf16)(o[mi][nt][r] * invl);
        }
}

// ---------------------------------------------------------------------------
extern "C" void kernel_launch(void* const* d_in, const int* in_sizes, int n_in,
                              void* d_out, int out_size, void* d_ws, size_t ws_size,
                              hipStream_t stream)
{
    const float* x  = (const float*)d_in[0];
    const float* WQ = (const float*)d_in[1];
    const float* WK = (const float*)d_in[2];
    const float* WV = (const float*)d_in[3];
    const float* WO = (const float*)d_in[4];
    const int*  pos = (const int*)d_in[5];

    // ws: Qw 8MB | Kw 2MB | Vt_g 2MB | xb/AO 8MB | Wqkv 3MB | WOb 2MB
    char* ws   = (char*)d_ws;
    bf16* Qw   = (bf16*)ws;
    bf16* Kw   = (bf16*)(ws + (size_t) 8 * 1024 * 1024);
    bf16* Vt_g = (bf16*)(ws + (size_t)10 * 1024 * 1024);
    bf16* xb   = (bf16*)(ws + (size_t)12 * 1024 * 1024);
    bf16* AO   = xb;                                        // overlay (xb dead)
    bf16* Wqkv = (bf16*)(ws + (size_t)20 * 1024 * 1024);
    bf16* WOb  = (bf16*)(ws + (size_t)23 * 1024 * 1024);

    const int cx = (M_ROWS * D_MODEL) / 8;
    const int cq = (D_MODEL * D_MODEL) / 8;
    const int ck = (KV_DIM * D_MODEL) / 8;
    const int ctot = cx + cq + 2 * ck + cq;
    convert_all<<<ctot / 256, 256, 0, stream>>>(
        x, xb, cx,
        WQ, Wqkv, cq,
        WK, Wqkv + (size_t)D_MODEL * D_MODEL, ck,
        WV, Wqkv + (size_t)(D_MODEL + KV_DIM) * D_MODEL, ck,
        WO, WOb, cq);

    // fused QKV projection + RoPE epilogue + V-transpose (1-D grid, XCD swz)
    gemm_t64<<<(N_QKV / 64) * (M_ROWS / 128), 256, 0, stream>>>(
        xb, Wqkv, D_MODEL, Qw, Kw, Vt_g, nullptr, pos, 0);

    // GQA-fused attention (P-in-register + permuted-V + setprio)
    attn_mfma<<<dim3(SEQ_T / 32, BATCH * NUM_GROUPS), 256, 0, stream>>>(
        Qw, Kw, Vt_g, AO);

    // output projection -> fp32 d_out (1-D grid, XCD swz)
    gemm_t64<<<(D_MODEL / 64) * (M_ROWS / 128), 256, 0, stream>>>(
        AO, WOb, D_MODEL, nullptr, nullptr, nullptr, (float*)d_out, pos, 1);
}